// Round 4
// baseline (76.607 us; speedup 1.0000x reference)
//
#include <hip/hip_runtime.h>
#include <hip/hip_fp16.h>

#define Rtot 65536
#define Wimg 256
#define Kp 64
#define NSTEPS 64
#define DTc (1.0f/256.0f)
#define INV_VOLR (1.0f/256.0f)
#define NITEMS 16384

// ws layout (bytes)
#define PD_OFF    0u          // 64 prims * 16 floats = 4 KB
#define TB_OFF    4096u       // 256 tiles * 16 floats = 16 KB
#define FLAG_OFF  20480u      // 16384 bytes
#define TT_OFF    65536u      // fp16 packed template: 64*4096*16 B = 4 MB
#define SBUF_OFF  8388608u    // fp16 s-buffer: 16384*256*8 B = 33.5 MB
#define WS_NEED   (SBUF_OFF + (size_t)NITEMS*256*8)

__device__ __forceinline__ unsigned int pack2(float a, float b) {
  __half2 h = __floats2half2_rn(a, b);
  return *(unsigned int*)&h;
}

// Fused setup:
//  blocks 0..255   : per-tile bounds of ray origin/dir/tmin -> tb
//  blocks 256..319 : repack template (K,4,16,16,16) f32 -> (K,4096) uint4 of
//                    8 fp16 {c0..c3 @ x, c0..c3 @ x+1}  (x+1 clamped)
//  block 320       : prim data (pos_n, rsc[i][j]=rot[i][j]*scale[j])
__global__ __launch_bounds__(256) void setup_kernel(
    const float* __restrict__ raypos, const float* __restrict__ raydir,
    const float* __restrict__ tminmax, const float* __restrict__ primpos,
    const float* __restrict__ primrot, const float* __restrict__ primscale,
    const float* __restrict__ tmpl,
    float* __restrict__ tb, uint4* __restrict__ tth, float* __restrict__ pd) {
  int bid = blockIdx.x, tid = threadIdx.x;
  if (bid < 256) {
    __shared__ float smn[4][7], smx[4][7];
    int w = (bid & 15)*16 + (tid & 15);
    int h = (bid >> 4)*16 + (tid >> 4);
    int r = h*Wimg + w;
    float v[7];
    v[0] = raypos[r*3+0]; v[1] = raypos[r*3+1]; v[2] = raypos[r*3+2];
    v[3] = raydir[r*3+0]; v[4] = raydir[r*3+1]; v[5] = raydir[r*3+2];
    v[6] = tminmax[r*2+0];
    float mn[7], mx[7];
#pragma unroll
    for (int i = 0; i < 7; ++i) { mn[i] = v[i]; mx[i] = v[i]; }
#pragma unroll
    for (int m = 1; m < 64; m <<= 1) {
#pragma unroll
      for (int i = 0; i < 7; ++i) {
        mn[i] = fminf(mn[i], __shfl_xor(mn[i], m));
        mx[i] = fmaxf(mx[i], __shfl_xor(mx[i], m));
      }
    }
    int wv = tid >> 6;
    if ((tid & 63) == 0) {
#pragma unroll
      for (int i = 0; i < 7; ++i) { smn[wv][i] = mn[i]; smx[wv][i] = mx[i]; }
    }
    __syncthreads();
    if (tid == 0) {
#pragma unroll
      for (int i = 0; i < 7; ++i) {
        tb[bid*16 + i]     = fminf(fminf(smn[0][i], smn[1][i]), fminf(smn[2][i], smn[3][i]));
        tb[bid*16 + 8 + i] = fmaxf(fmaxf(smx[0][i], smx[1][i]), fmaxf(smx[2][i], smx[3][i]));
      }
    }
  } else if (bid < 320) {
    int k = bid - 256;
    const float* b0 = tmpl + (((size_t)k) << 14);
    uint4* o = tth + (k << 12);
    for (int v = tid; v < 4096; v += 256) {
      int x = v & 15;
      int xn = (x < 15) ? v + 1 : v;
      uint4 q;
      q.x = pack2(b0[v],       b0[4096+v]);
      q.y = pack2(b0[8192+v],  b0[12288+v]);
      q.z = pack2(b0[xn],      b0[4096+xn]);
      q.w = pack2(b0[8192+xn], b0[12288+xn]);
      o[v] = q;
    }
  } else {
    int k = tid;
    if (k < Kp) {
      float sc0 = primscale[k*3+0], sc1 = primscale[k*3+1], sc2 = primscale[k*3+2];
      float* o = pd + (k << 4);
      o[0] = primpos[k*3+0] * INV_VOLR;
      o[1] = primpos[k*3+1] * INV_VOLR;
      o[2] = primpos[k*3+2] * INV_VOLR;
      o[3] = 0.0f; o[4] = 0.0f; o[5] = 0.0f;
#pragma unroll
      for (int i = 0; i < 3; ++i) {
        o[6+i*3+0] = primrot[k*9+i*3+0]*sc0;
        o[6+i*3+1] = primrot[k*9+i*3+1]*sc1;
        o[6+i*3+2] = primrot[k*9+i*3+2]*sc2;
      }
      o[15] = 0.0f;
    }
  }
}

// Per-prim transform + trilinear setup (branchless; weights zeroed if outside).
__device__ __forceinline__ void prim_setup(const float* __restrict__ p,
    float px, float py, float pz, bool& inside, const uint4*& addr,
    float& wx0, float& wfx, float& w00, float& w01, float& w10, float& w11,
    const uint4* __restrict__ tth, int k) {
  float relx = px - p[0], rely = py - p[1], relz = pz - p[2];
  float lx = relx*p[6] + rely*p[9]  + relz*p[12];
  float ly = relx*p[7] + rely*p[10] + relz*p[13];
  float lz = relx*p[8] + rely*p[11] + relz*p[14];
  inside = fabsf(lx) < 1.0f && fabsf(ly) < 1.0f && fabsf(lz) < 1.0f;
  float gx = fminf(fmaxf((lx + 1.0f)*7.5f, 0.0f), 14.99999f);
  float gy = fminf(fmaxf((ly + 1.0f)*7.5f, 0.0f), 14.99999f);
  float gz = fminf(fmaxf((lz + 1.0f)*7.5f, 0.0f), 14.99999f);
  int ix = (int)gx, iy = (int)gy, iz = (int)gz;
  ix = ix > 14 ? 14 : ix; iy = iy > 14 ? 14 : iy; iz = iz > 14 ? 14 : iz;
  float fx = gx - (float)ix, fy = gy - (float)iy, fz = gz - (float)iz;
  float m = inside ? 1.0f : 0.0f;
  wx0 = 1.0f - fx; wfx = fx;
  float wy0 = 1.0f - fy, wz0 = 1.0f - fz;
  w00 = wz0*wy0*m; w01 = wz0*fy*m; w10 = fz*wy0*m; w11 = fz*fy*m;
  addr = tth + ((size_t)k << 12) + iz*256 + iy*16 + ix;
}

#define ACCQ(q, wv, wx0, wfx) { \
  float2 p01 = __half22float2(*(const __half2*)&q.x); \
  float2 p23 = __half22float2(*(const __half2*)&q.y); \
  float2 n01 = __half22float2(*(const __half2*)&q.z); \
  float2 n23 = __half22float2(*(const __half2*)&q.w); \
  float wa = (wv)*(wx0), wb = (wv)*(wfx); \
  c0 = fmaf(p01.x, wa, fmaf(n01.x, wb, c0)); \
  c1 = fmaf(p01.y, wa, fmaf(n01.y, wb, c1)); \
  c2 = fmaf(p23.x, wa, fmaf(n23.x, wb, c2)); \
  c3 = fmaf(p23.y, wa, fmaf(n23.y, wb, c3)); }

// Shade: one block per (tile,step). Wave 0 culls prims in PRIM-LOCAL space;
// every block writes its flag; empties exit; survivors shade 256 rays with a
// 2-wide software-pipelined prim loop (8 gathers in flight).
__global__ __launch_bounds__(256) void shade_kernel(
    const float* __restrict__ raypos, const float* __restrict__ raydir,
    const float* __restrict__ tminmax, const float* __restrict__ pd,
    const float* __restrict__ tb, const uint4* __restrict__ tth,
    uint2* __restrict__ sbuf, unsigned char* __restrict__ flags) {
  __shared__ int s_list[Kp];
  __shared__ int s_cnt;
  int item = blockIdx.x;
  int tile = item >> 6, step = item & 63;
  int tid = threadIdx.x;
  if (tid < 64) {
    const float* t0 = tb + tile*16;
    float cst = ((float)step + 0.5f)*DTc;
    float tl = t0[6] + cst, th = t0[14] + cst;
    const float* p = pd + (tid << 4);
    float rlo[3], rhi[3];
#pragma unroll
    for (int a = 0; a < 3; ++a) {
      float ol = t0[a], oh = t0[8+a], dl = t0[3+a], dh = t0[11+a];
      float p1 = tl*dl, p2 = tl*dh, p3 = th*dl, p4 = th*dh;
      float lo = ol + fminf(fminf(p1, p2), fminf(p3, p4));
      float hi = oh + fmaxf(fmaxf(p1, p2), fmaxf(p3, p4));
      rlo[a] = lo - p[a];
      rhi[a] = hi - p[a];
    }
    bool pass = true;
#pragma unroll
    for (int j = 0; j < 3; ++j) {
      float llo = 0.f, lhi = 0.f;
#pragma unroll
      for (int a = 0; a < 3; ++a) {
        float rsc = p[6+a*3+j];
        float q1 = rlo[a]*rsc, q2 = rhi[a]*rsc;
        llo += fminf(q1, q2);
        lhi += fmaxf(q1, q2);
      }
      pass = pass && (llo < 1.0f) && (lhi > -1.0f);
    }
    unsigned long long mask = __ballot(pass);
    if (tid == 0) s_cnt = (int)__popcll(mask);
    if (pass) {
      int pos = (int)__popcll(mask & ((1ull << tid) - 1ull));
      s_list[pos] = tid;
    }
  }
  __syncthreads();
  int cnt = s_cnt;
  if (tid == 0) flags[item] = (unsigned char)(cnt > 0 ? 1 : 0);
  if (cnt == 0) return;

  int w = (tile & 15)*16 + (tid & 15);
  int h = (tile >> 4)*16 + (tid >> 4);
  int r = h*Wimg + w;
  float t = tminmax[r*2] + ((float)step + 0.5f)*DTc;
  float px = fmaf(t, raydir[r*3+0], raypos[r*3+0]);
  float py = fmaf(t, raydir[r*3+1], raypos[r*3+1]);
  float pz = fmaf(t, raydir[r*3+2], raypos[r*3+2]);
  float c0 = 0.f, c1 = 0.f, c2 = 0.f, c3 = 0.f;

  int j = 0;
  for (; j + 1 < cnt; j += 2) {
    int k0 = __builtin_amdgcn_readfirstlane(s_list[j]);
    int k1 = __builtin_amdgcn_readfirstlane(s_list[j+1]);
    bool in0, in1;
    const uint4 *a0, *a1;
    float wx0a, wfxa, w00a, w01a, w10a, w11a;
    float wx0b, wfxb, w00b, w01b, w10b, w11b;
    prim_setup(pd + (k0 << 4), px, py, pz, in0, a0, wx0a, wfxa, w00a, w01a, w10a, w11a, tth, k0);
    prim_setup(pd + (k1 << 4), px, py, pz, in1, a1, wx0b, wfxb, w00b, w01b, w10b, w11b, tth, k1);
    if (__any(in0 || in1)) {
      uint4 q00 = a0[0], q01 = a0[16], q10 = a0[256], q11 = a0[272];
      uint4 r00 = a1[0], r01 = a1[16], r10 = a1[256], r11 = a1[272];
      ACCQ(q00, w00a, wx0a, wfxa) ACCQ(q01, w01a, wx0a, wfxa)
      ACCQ(q10, w10a, wx0a, wfxa) ACCQ(q11, w11a, wx0a, wfxa)
      ACCQ(r00, w00b, wx0b, wfxb) ACCQ(r01, w01b, wx0b, wfxb)
      ACCQ(r10, w10b, wx0b, wfxb) ACCQ(r11, w11b, wx0b, wfxb)
    }
  }
  if (j < cnt) {
    int k0 = __builtin_amdgcn_readfirstlane(s_list[j]);
    bool in0;
    const uint4* a0;
    float wx0a, wfxa, w00a, w01a, w10a, w11a;
    prim_setup(pd + (k0 << 4), px, py, pz, in0, a0, wx0a, wfxa, w00a, w01a, w10a, w11a, tth, k0);
    if (__any(in0)) {
      uint4 q00 = a0[0], q01 = a0[16], q10 = a0[256], q11 = a0[272];
      ACCQ(q00, w00a, wx0a, wfxa) ACCQ(q01, w01a, wx0a, wfxa)
      ACCQ(q10, w10a, wx0a, wfxa) ACCQ(q11, w11a, wx0a, wfxa)
    }
  }
  sbuf[item*256 + tid] = make_uint2(pack2(c0, c1), pack2(c2, c3));
}

// Composite: one thread per ray; flag-gated sbuf loads (uniform branch).
__global__ __launch_bounds__(256) void composite_kernel(
    const float* __restrict__ tminmax, const uint2* __restrict__ sbuf,
    const unsigned char* __restrict__ flags, float* __restrict__ out) {
  __shared__ unsigned char s_flags[NSTEPS];
  int tid = threadIdx.x;
  int b = blockIdx.x;
  if (tid < NSTEPS) s_flags[tid] = flags[b*NSTEPS + tid];
  __syncthreads();
  int w = (b & 15)*16 + (tid & 15);
  int h = (b >> 4)*16 + (tid >> 4);
  int r = h*Wimg + w;
  float tmin = tminmax[r*2+0], tmax = tminmax[r*2+1];
  float rgb0 = 0.f, rgb1 = 0.f, rgb2 = 0.f, alpha = 0.f;
  for (int i = 0; i < NSTEPS; ++i) {
    float s0 = 0.f, s1 = 0.f, s2 = 0.f, s3 = 0.f;
    if (s_flags[i]) {
      uint2 pk = sbuf[(b*NSTEPS + i)*256 + tid];
      float2 lf = __half22float2(*(__half2*)&pk.x);
      float2 hf = __half22float2(*(__half2*)&pk.y);
      s0 = lf.x; s1 = lf.y; s2 = hf.x; s3 = hf.y;
    }
    float t = tmin + ((float)i + 0.5f)*DTc;
    float contrib = fminf(1.0f, fmaf(s3, DTc, alpha)) - alpha;
    contrib = (t < tmax) ? contrib : 0.0f;
    rgb0 = fmaf(s0, contrib, rgb0);
    rgb1 = fmaf(s1, contrib, rgb1);
    rgb2 = fmaf(s2, contrib, rgb2);
    alpha += contrib;
  }
  out[0*Rtot + r] = rgb0;
  out[1*Rtot + r] = rgb1;
  out[2*Rtot + r] = rgb2;
  out[3*Rtot + r] = alpha;
  out[4*Rtot + r] = rgb0;
  out[5*Rtot + r] = rgb1;
  out[6*Rtot + r] = rgb2;
  out[7*Rtot + r] = alpha;
}

// Self-contained fallback (no workspace): one thread per ray, all prims.
__global__ __launch_bounds__(256) void fallback_kernel(
    const float* __restrict__ raypos, const float* __restrict__ raydir,
    const float* __restrict__ tminmax,
    const float* __restrict__ primpos, const float* __restrict__ primrot,
    const float* __restrict__ primscale, const float* __restrict__ tmpl,
    float* __restrict__ out) {
  __shared__ float s_pd[Kp][16];
  int tx = threadIdx.x, ty = threadIdx.y;
  int tid = ty*16 + tx;
  if (tid < Kp) {
    int k = tid;
    float sc0 = primscale[k*3+0], sc1 = primscale[k*3+1], sc2 = primscale[k*3+2];
    s_pd[k][0] = primpos[k*3+0]*INV_VOLR;
    s_pd[k][1] = primpos[k*3+1]*INV_VOLR;
    s_pd[k][2] = primpos[k*3+2]*INV_VOLR;
#pragma unroll
    for (int i = 0; i < 3; ++i) {
      s_pd[k][6+i*3+0] = primrot[k*9+i*3+0]*sc0;
      s_pd[k][6+i*3+1] = primrot[k*9+i*3+1]*sc1;
      s_pd[k][6+i*3+2] = primrot[k*9+i*3+2]*sc2;
    }
  }
  __syncthreads();
  int w = blockIdx.x*16 + tx, h = blockIdx.y*16 + ty;
  int r = h*Wimg + w;
  float ox = raypos[r*3+0], oy = raypos[r*3+1], oz = raypos[r*3+2];
  float dx = raydir[r*3+0], dy = raydir[r*3+1], dz = raydir[r*3+2];
  float tmin = tminmax[r*2+0], tmax = tminmax[r*2+1];
  float rgb0=0.f, rgb1=0.f, rgb2=0.f, alpha=0.f;
  for (int i = 0; i < NSTEPS; ++i) {
    float t = tmin + ((float)i + 0.5f)*DTc;
    float px = fmaf(t, dx, ox), py = fmaf(t, dy, oy), pz = fmaf(t, dz, oz);
    float c[4] = {0.f, 0.f, 0.f, 0.f};
    for (int k = 0; k < Kp; ++k) {
      const float* p = &s_pd[k][0];
      float relx = px - p[0], rely = py - p[1], relz = pz - p[2];
      float lx = relx*p[6] + rely*p[9]  + relz*p[12];
      float ly = relx*p[7] + rely*p[10] + relz*p[13];
      float lz = relx*p[8] + rely*p[11] + relz*p[14];
      if (!(fabsf(lx) < 1.0f && fabsf(ly) < 1.0f && fabsf(lz) < 1.0f)) continue;
      float gx = fminf(fmaxf((lx + 1.0f)*7.5f, 0.0f), 14.99999f);
      float gy = fminf(fmaxf((ly + 1.0f)*7.5f, 0.0f), 14.99999f);
      float gz = fminf(fmaxf((lz + 1.0f)*7.5f, 0.0f), 14.99999f);
      int ix = (int)gx, iy = (int)gy, iz = (int)gz;
      ix = ix > 14 ? 14 : ix; iy = iy > 14 ? 14 : iy; iz = iz > 14 ? 14 : iz;
      float fx = gx - (float)ix, fy = gy - (float)iy, fz = gz - (float)iz;
      float wx0 = 1.0f - fx, wy0 = 1.0f - fy, wz0 = 1.0f - fz;
      float w00 = wz0*wy0, w01 = wz0*fy, w10 = fz*wy0, w11 = fz*fy;
      const float* base = tmpl + (((size_t)k) << 14) + iz*256 + iy*16 + ix;
#pragma unroll
      for (int ch = 0; ch < 4; ++ch) {
        const float* bb = base + ch*4096;
        c[ch] += (bb[0]  *wx0 + bb[1]  *fx) * w00
               + (bb[16] *wx0 + bb[17] *fx) * w01
               + (bb[256]*wx0 + bb[257]*fx) * w10
               + (bb[272]*wx0 + bb[273]*fx) * w11;
      }
    }
    float contrib = fminf(1.0f, fmaf(c[3], DTc, alpha)) - alpha;
    contrib = (t < tmax) ? contrib : 0.0f;
    rgb0 = fmaf(c[0], contrib, rgb0);
    rgb1 = fmaf(c[1], contrib, rgb1);
    rgb2 = fmaf(c[2], contrib, rgb2);
    alpha += contrib;
  }
  out[0*Rtot + r] = rgb0;
  out[1*Rtot + r] = rgb1;
  out[2*Rtot + r] = rgb2;
  out[3*Rtot + r] = alpha;
  out[4*Rtot + r] = rgb0;
  out[5*Rtot + r] = rgb1;
  out[6*Rtot + r] = rgb2;
  out[7*Rtot + r] = alpha;
}

extern "C" void kernel_launch(void* const* d_in, const int* in_sizes, int n_in,
                              void* d_out, int out_size, void* d_ws, size_t ws_size,
                              hipStream_t stream) {
  const float* raypos    = (const float*)d_in[0];
  const float* raydir    = (const float*)d_in[1];
  const float* tminmax   = (const float*)d_in[2];
  const float* primpos   = (const float*)d_in[3];
  const float* primrot   = (const float*)d_in[4];
  const float* primscale = (const float*)d_in[5];
  const float* primrgba  = (const float*)d_in[6];
  float* out = (float*)d_out;

  if (ws_size >= WS_NEED) {
    char* ws = (char*)d_ws;
    float* pd            = (float*)(ws + PD_OFF);
    float* tb            = (float*)(ws + TB_OFF);
    unsigned char* flags = (unsigned char*)(ws + FLAG_OFF);
    uint4* tth           = (uint4*)(ws + TT_OFF);
    uint2* sbuf          = (uint2*)(ws + SBUF_OFF);

    setup_kernel<<<321, 256, 0, stream>>>(raypos, raydir, tminmax, primpos,
                                          primrot, primscale, primrgba,
                                          tb, tth, pd);
    shade_kernel<<<NITEMS, 256, 0, stream>>>(raypos, raydir, tminmax, pd, tb,
                                             tth, sbuf, flags);
    composite_kernel<<<256, 256, 0, stream>>>(tminmax, sbuf, flags, out);
  } else {
    fallback_kernel<<<dim3(16,16), dim3(16,16), 0, stream>>>(
        raypos, raydir, tminmax, primpos, primrot, primscale, primrgba, out);
  }
}